// Round 9
// baseline (193.383 us; speedup 1.0000x reference)
//
#include <hip/hip_runtime.h>
#include <hip/hip_bf16.h>

// B=2, N=2048, C=1024, H=16, hd=64, M=4096. bf16 MFMA path (threshold 2%).

typedef __attribute__((ext_vector_type(8))) short short8;
typedef __attribute__((ext_vector_type(4))) short short4v;
typedef __attribute__((ext_vector_type(4))) float float4v;
typedef __attribute__((ext_vector_type(4))) unsigned uint4v;

__device__ __forceinline__ unsigned short f2bf(float f) {   // RTNE
    unsigned u = __builtin_bit_cast(unsigned, f);
    return (unsigned short)((u + 0x7FFFu + ((u >> 16) & 1u)) >> 16);
}
// hardware packed f32->bf16 (RTNE), lo in low half
__device__ __forceinline__ unsigned cvtpk(float lo, float hi) {
    unsigned r;
    asm("v_cvt_pk_bf16_f32 %0, %1, %2" : "=v"(r) : "v"(lo), "v"(hi));
    return r;
}
__device__ __forceinline__ void gll16(const unsigned short* g, unsigned short* l) {
    __builtin_amdgcn_global_load_lds(
        (const __attribute__((address_space(1))) unsigned int*)g,
        (__attribute__((address_space(3))) unsigned int*)l, 16, 0, 0);
}

// ---------------- prep v2: LN1 wave-per-row (blocks 0..1023, 4 rows/block —
// no __syncthreads, no LDS in the LN path) + weight transposes (1024..5119).
__global__ __launch_bounds__(256) void prep(
    const float* __restrict__ x, const float* __restrict__ g1, const float* __restrict__ b1,
    const float* __restrict__ w_qk, const float* __restrict__ w_v,
    const float* __restrict__ w_proj, const float* __restrict__ g2,
    const float* __restrict__ b2,
    unsigned short* __restrict__ xn, unsigned short* __restrict__ wqkvT,
    unsigned short* __restrict__ wgT, float* __restrict__ u, float* __restrict__ w0) {
    __shared__ float sh[32 * 33];
    const int bid = blockIdx.x, tid = threadIdx.x;
    if (bid < 1024) {                       // ---- LN1: one wave per row
        const int lane = tid & 63;
        const int row = bid * 4 + (tid >> 6);
        const float4* xr = reinterpret_cast<const float4*>(x + (size_t)row * 1024);
        const float4* G4 = reinterpret_cast<const float4*>(g1);
        const float4* B4 = reinterpret_cast<const float4*>(b1);
        float4 v[4];
        float s = 0.f, sq = 0.f;
#pragma unroll
        for (int i = 0; i < 4; i++) {
            v[i] = xr[i * 64 + lane];
            s  += (v[i].x + v[i].y) + (v[i].z + v[i].w);
            sq += (v[i].x * v[i].x + v[i].y * v[i].y) + (v[i].z * v[i].z + v[i].w * v[i].w);
        }
#pragma unroll
        for (int off = 32; off >= 1; off >>= 1) {
            s  += __shfl_xor(s, off, 64);
            sq += __shfl_xor(sq, off, 64);
        }
        const float mu = s * (1.f / 1024.f);
        const float rstd = rsqrtf(sq * (1.f / 1024.f) - mu * mu + 1e-5f);
#pragma unroll
        for (int i = 0; i < 4; i++) {
            const float4 gv = G4[i * 64 + lane], bv = B4[i * 64 + lane];
            ushort4 o;
            o.x = f2bf((v[i].x - mu) * rstd * gv.x + bv.x);
            o.y = f2bf((v[i].y - mu) * rstd * gv.y + bv.y);
            o.z = f2bf((v[i].z - mu) * rstd * gv.z + bv.z);
            o.w = f2bf((v[i].w - mu) * rstd * gv.w + bv.w);
            *reinterpret_cast<ushort4*>(&xn[(size_t)row * 1024 + i * 256 + lane * 4]) = o;
        }
    } else {                                // ---- transpose f32[1024][Cc] -> bf16[Cc][1024]
        const float* in; unsigned short* out; int Cc, bx, by; bool doU = false;
        if (bid < 3072)      { int t = bid - 1024; in = w_qk;   out = wqkvT;               Cc = 2048; bx = t & 63; by = t >> 6; }
        else if (bid < 4096) { int t = bid - 3072; in = w_v;    out = wqkvT + 2048 * 1024; Cc = 1024; bx = t & 31; by = t >> 5; }
        else                 { int t = bid - 4096; in = w_proj; out = wgT; doU = true;     Cc = 1024; bx = t & 31; by = t >> 5; }
        const int c0 = bx * 32, r0 = by * 32;
        const int tx = tid & 31, ty = tid >> 5;
#pragma unroll
        for (int i = 0; i < 32; i += 8)
            sh[(ty + i) * 33 + tx] = in[(size_t)(r0 + ty + i) * Cc + c0 + tx];
        __syncthreads();
        // out col = original row index c = r0+tx
        const float scale = doU ? g2[r0 + tx] : 1.f;
        const float b2v   = doU ? b2[r0 + tx] : 0.f;
#pragma unroll
        for (int i = 0; i < 32; i += 8) {
            const float raw = sh[tx * 33 + ty + i];
            const float sc  = raw * scale;
            out[(size_t)(c0 + ty + i) * 1024 + r0 + tx] = f2bf(sc);
            if (doU) {
                float pu = sc, pw = raw * b2v;    // per-c contributions for j=c0+ty+i
#pragma unroll
                for (int off = 1; off <= 16; off <<= 1) {   // reduce over tx (32 lanes)
                    pu += __shfl_xor(pu, off, 64);
                    pw += __shfl_xor(pw, off, 64);
                }
                if (tx == 0) {
                    atomicAdd(&u[c0 + ty + i], pu);
                    atomicAdd(&w0[c0 + ty + i], pw);
                }
            }
        }
    }
}

// ---------------- GEMM1 v4 (R7-verified, sub-48): 128(m) x 192(n) tile,
// 512 thr / 8 waves (2m x 4n, acc 4x3), BK=64, 2-dbuf. LDS 80 KB ->
// 2 blocks/CU; grid 16x32 = 512 = exactly 2/CU, uniform. Unchanged.
__global__ __launch_bounds__(512, 2) void gemm_qkv(const unsigned short* __restrict__ A,
                                                   const unsigned short* __restrict__ Bt,
                                                   unsigned short* __restrict__ qb,
                                                   unsigned short* __restrict__ kb,
                                                   unsigned short* __restrict__ vT) {
    __shared__ unsigned short As[2 * 128 * 64];   // 32 KB
    __shared__ unsigned short Bs[2 * 192 * 64];   // 48 KB
    const int tid = threadIdx.x, lane = tid & 63, w = tid >> 6;     // w 0..7
    const int wm = (w >> 2) * 64, wn = (w & 3) * 48;
    const int quad = lane >> 4, l16 = lane & 15;
    const int ls = lane >> 3, sg = lane & 7;
    const int m0 = blockIdx.y * 128, n0 = blockIdx.x * 192;

    float4v acc[4][3];
#pragma unroll
    for (int mi = 0; mi < 4; mi++)
#pragma unroll
        for (int ni = 0; ni < 3; ni++) acc[mi][ni] = float4v{0.f, 0.f, 0.f, 0.f};

    const int g = (sg ^ ls) * 8;
    // stage step 0: per wave 16 A-rows (2 gll16) + 24 B-rows (3 gll16)
#pragma unroll
    for (int i = 0; i < 2; i++)
        gll16(&A[(size_t)(m0 + w * 16 + i * 8 + ls) * 1024 + g], &As[(w * 16 + i * 8) * 64]);
#pragma unroll
    for (int i = 0; i < 3; i++)
        gll16(&Bt[(size_t)(n0 + w * 24 + i * 8 + ls) * 1024 + g], &Bs[(w * 24 + i * 8) * 64]);

#pragma unroll 1
    for (int s = 0; s < 16; s++) {
        __syncthreads();
        if (s + 1 < 16) {                   // stage step s+1 (overlaps compute(s))
            const int k0 = (s + 1) << 6;
            unsigned short* Ad = As + (((s + 1) & 1) << 13);
            unsigned short* Bd = Bs + (((s + 1) & 1) * 12288);
#pragma unroll
            for (int i = 0; i < 2; i++)
                gll16(&A[(size_t)(m0 + w * 16 + i * 8 + ls) * 1024 + k0 + g],
                      &Ad[(w * 16 + i * 8) * 64]);
#pragma unroll
            for (int i = 0; i < 3; i++)
                gll16(&Bt[(size_t)(n0 + w * 24 + i * 8 + ls) * 1024 + k0 + g],
                      &Bd[(w * 24 + i * 8) * 64]);
        }
        const unsigned short* Ac = As + ((s & 1) << 13);
        const unsigned short* Bc = Bs + ((s & 1) * 12288);
#pragma unroll
        for (int ks = 0; ks < 2; ks++) {
            short8 af[4], bfr[3];
#pragma unroll
            for (int mi = 0; mi < 4; mi++) {
                const int r = wm + mi * 16 + l16;
                af[mi] = *reinterpret_cast<const short8*>(
                    &Ac[r * 64 + ((ks * 4 + quad) ^ (r & 7)) * 8]);
            }
#pragma unroll
            for (int ni = 0; ni < 3; ni++) {
                const int r = wn + ni * 16 + l16;
                bfr[ni] = *reinterpret_cast<const short8*>(
                    &Bc[r * 64 + ((ks * 4 + quad) ^ (r & 7)) * 8]);
            }
#pragma unroll
            for (int mi = 0; mi < 4; mi++)
#pragma unroll
                for (int ni = 0; ni < 3; ni++)
                    acc[mi][ni] = __builtin_amdgcn_mfma_f32_16x16x32_bf16(
                        af[mi], bfr[ni], acc[mi][ni], 0, 0, 0);
        }
    }

    const float QSCALE = 0.125f * 1.4426950408889634f;  // hd^-0.5 * log2(e)
#pragma unroll
    for (int mi = 0; mi < 4; mi++) {
        const int row0 = m0 + wm + mi * 16 + quad * 4;
        const int b = row0 >> 11, nq = row0 & 2047;
#pragma unroll
        for (int ni = 0; ni < 3; ni++) {
            const int col = n0 + wn + ni * 16 + l16;
            if (col < 1024) {             // q: [bh][n][d]
                const int h = col >> 6, d = col & 63;
#pragma unroll
                for (int r = 0; r < 4; r++)
                    qb[(((size_t)b * 16 + h) * 2048 + nq + r) * 64 + d] =
                        f2bf(acc[mi][ni][r] * QSCALE);
            } else if (col < 2048) {      // k: [bh][n][d]
                const int c = col - 1024, h = c >> 6, d = c & 63;
#pragma unroll
                for (int r = 0; r < 4; r++)
                    kb[(((size_t)b * 16 + h) * 2048 + nq + r) * 64 + d] = f2bf(acc[mi][ni][r]);
            } else {                      // v^T: [bh][d][n], 4 consecutive keys -> 8B store
                const int c = col - 2048, h = c >> 6, d = c & 63;
                const short4v sv = {(short)f2bf(acc[mi][ni][0]), (short)f2bf(acc[mi][ni][1]),
                                    (short)f2bf(acc[mi][ni][2]), (short)f2bf(acc[mi][ni][3])};
                *reinterpret_cast<short4v*>(
                    &vT[(((size_t)b * 16 + h) * 64 + d) * 2048 + nq]) = sv;
            }
        }
    }
}

// ---------------- flash attention v12: LDS-read amortization. v10/v11's
// 8 waves each read 8 ds_read_b128/tile to feed only 2 q-blocks — all 4 wq
// waves read IDENTICAL fragments (4x redundancy; 20.5 us/CU of LDS issue,
// the largest pipe in the 47 us kernel). Now 256 thr / 4 waves: wq=w&1 owns
// 64 q rows (q2=0..3), kh=w>>1 owns a 32-key half. Same 8 reads/tile/wave
// feed 2x the MFMA -> program-wide LDS-read issue HALVES (~10 us/CU).
// Residency drops to 8 waves/CU, compensated by 4 independent per-wave
// MFMA->exp2->pack chains (ILP instead of TLP). Staging + combine epilogue
// cloned from v9 (R4, verified correct), q2 extended 2->4.
__global__ __launch_bounds__(256) void flash_attn(const unsigned short* __restrict__ qbuf,
                                                  const unsigned short* __restrict__ kb,
                                                  const unsigned short* __restrict__ vT,
                                                  unsigned short* __restrict__ attn,
                                                  float2* __restrict__ part) {
    __shared__ __align__(16) unsigned short KV[4][64 * 64];  // [0..1]=K dbuf [2..3]=V dbuf, 32 KB
    __shared__ float lsh[2][4][64];                          // l partials kh=1 -> kh=0, 2 KB
    const int tid = threadIdx.x, lane = tid & 63, w = tid >> 6;   // w 0..3
    const int wq = w & 1, kh = w >> 1;
    const int quad = lane >> 4, l16 = lane & 15;
    const int ls = lane >> 3, sg = lane & 7;
    const int bh = blockIdx.x, q0 = blockIdx.y * 128;
    const size_t nbase = (size_t)bh * 2048;

    // K staging source rows: phys row pr holds actual key ka(pr)
    int srow[2];
#pragma unroll
    for (int i = 0; i < 2; i++) {
        const int pr = w * 16 + i * 8 + ls;
        srow[i] = (pr & 32) | ((pr & 12) << 1) | ((pr & 16) >> 2) | (pr & 3);
    }
    const int sgran = (sg ^ ls) << 3;

    short8 bq[4][2];   // Q as B-operand, q = q0 + wq*64 + q2*16 + l16
#pragma unroll
    for (int q2 = 0; q2 < 4; q2++)
#pragma unroll
        for (int ks = 0; ks < 2; ks++)
            bq[q2][ks] = *reinterpret_cast<const short8*>(
                &qbuf[(nbase + q0 + wq * 64 + q2 * 16 + l16) * 64 + ks * 32 + quad * 8]);

    float l_part[4] = {0.f, 0.f, 0.f, 0.f};
    float4v o_acc[4][4];   // o_acc[q2][db]: d = db*16+quad*4+reg, q = l16 (partial: kh half)
#pragma unroll
    for (int q2 = 0; q2 < 4; q2++)
#pragma unroll
        for (int db = 0; db < 4; db++) o_acc[q2][db] = float4v{0.f, 0.f, 0.f, 0.f};

    // stage tile 0 (K permuted; V rows d = w*16+i*8+ls)
#pragma unroll
    for (int i = 0; i < 2; i++) {
        gll16(&kb[(nbase + srow[i]) * 64 + sgran], &KV[0][(w * 16 + i * 8) * 64]);
        gll16(&vT[((size_t)bh * 64 + w * 16 + i * 8 + ls) * 2048 + sgran],
              &KV[2][(w * 16 + i * 8) * 64]);
    }

#pragma unroll 1
    for (int s = 0; s < 32; s++) {
        __syncthreads();                    // drains tile-s DMA
        if (s + 1 < 32) {                   // stage tile s+1 (drained next barrier)
            const int ktn = (s + 1) << 6, buf = (s + 1) & 1;
#pragma unroll
            for (int i = 0; i < 2; i++) {
                gll16(&kb[(nbase + ktn + srow[i]) * 64 + sgran],
                      &KV[buf][(w * 16 + i * 8) * 64]);
                gll16(&vT[((size_t)bh * 64 + w * 16 + i * 8 + ls) * 2048 + ktn + sgran],
                      &KV[2 + buf][(w * 16 + i * 8) * 64]);
            }
        }
        const unsigned short* Kc = KV[s & 1];
        const unsigned short* Vc = KV[2 + (s & 1)];

        // this wave's 32-key half: phys rows kh*32 + cc*16 + l16
        short8 kf[2][2];
#pragma unroll
        for (int ks = 0; ks < 2; ks++)
#pragma unroll
            for (int cc = 0; cc < 2; cc++) {
                const int r = kh * 32 + cc * 16 + l16;
                kf[ks][cc] = *reinterpret_cast<const short8*>(
                    &Kc[r * 64 + ((ks * 4 + quad) ^ (r & 7)) * 8]);
            }
        // V^T A-fragments for this key half: A[d=db*16+l16][k = kh*32 + quad*8 + j]
        short8 va[4];
#pragma unroll
        for (int db = 0; db < 4; db++) {
            const int r = db * 16 + l16;
            va[db] = *reinterpret_cast<const short8*>(
                &Vc[r * 64 + ((kh * 4 + quad) ^ (r & 7)) * 8]);
        }

#pragma unroll
        for (int q2 = 0; q2 < 4; q2++) {
            float4v s_acc[2];
#pragma unroll
            for (int cc = 0; cc < 2; cc++) s_acc[cc] = float4v{0.f, 0.f, 0.f, 0.f};
            __builtin_amdgcn_s_setprio(1);
#pragma unroll
            for (int ks = 0; ks < 2; ks++)
#pragma unroll
                for (int cc = 0; cc < 2; cc++)
                    s_acc[cc] = __builtin_amdgcn_mfma_f32_16x16x32_bf16(
                        kf[ks][cc], bq[q2][ks], s_acc[cc], 0, 0, 0);
            __builtin_amdgcn_s_setprio(0);

            // fixed-max softmax: p = 2^s. Permuted K rows make the pack
            // register-local: actual key = kh*32 + quad*8 + cc*4 + reg.
            float ls2 = 0.f;
            float p[8];
#pragma unroll
            for (int cc = 0; cc < 2; cc++)
#pragma unroll
                for (int r = 0; r < 4; r++) {
                    const float pv = __builtin_amdgcn_exp2f(s_acc[cc][r]);
                    p[cc * 4 + r] = pv;
                    ls2 += pv;
                }
            uint4v pd;
            pd.x = cvtpk(p[0], p[1]); pd.y = cvtpk(p[2], p[3]);
            pd.z = cvtpk(p[4], p[5]); pd.w = cvtpk(p[6], p[7]);
            const short8 pb = __builtin_bit_cast(short8, pd);
            l_part[q2] += ls2;
            __builtin_amdgcn_s_setprio(1);
#pragma unroll
            for (int db = 0; db < 4; db++)
                o_acc[q2][db] = __builtin_amdgcn_mfma_f32_16x16x32_bf16(
                    va[db], pb, o_acc[q2][db], 0, 0, 0);
            __builtin_amdgcn_s_setprio(0);
        }
    }

    // ---- combine key halves through LDS (K/V buffers are dead now).
    __syncthreads();                        // all waves done reading KV
    float* osh = reinterpret_cast<float*>(KV);   // 8192 floats = 32 KB exactly (128q x 64d)
    const int swz = (l16 & 7) << 2;              // 16B-granule XOR to spread banks
    if (kh == 1) {
#pragma unroll
        for (int q2 = 0; q2 < 4; q2++) {
#pragma unroll
            for (int db = 0; db < 4; db++) {
                const int base = (wq * 64 + q2 * 16 + l16) * 64 + db * 16 + quad * 4;
                *reinterpret_cast<float4v*>(&osh[base ^ swz]) = o_acc[q2][db];
            }
            lsh[wq][q2][lane] = l_part[q2];
        }
    }
    __syncthreads();
    if (kh == 0) {
        const int b = bh >> 4, h = bh & 15;
#pragma unroll
        for (int q2 = 0; q2 < 4; q2++) {
            float lr = l_part[q2] + lsh[wq][q2][lane];
            lr += __shfl_xor(lr, 16, 64);
            lr += __shfl_xor(lr, 32, 64);
            const float inv = 1.f / lr;
            const int grow = b * 2048 + q0 + wq * 64 + q2 * 16 + l16;
            float sum = 0.f, s2 = 0.f;
#pragma unroll
            for (int db = 0; db < 4; db++) {
                const int base = (wq * 64 + q2 * 16 + l16) * 64 + db * 16 + quad * 4;
                const float4v oh = *reinterpret_cast<const float4v*>(&osh[base ^ swz]);
                const float o0 = (o_acc[q2][db][0] + oh[0]) * inv;
                const float o1 = (o_acc[q2][db][1] + oh[1]) * inv;
                const float o2 = (o_acc[q2][db][2] + oh[2]) * inv;
                const float o3 = (o_acc[q2][db][3] + oh[3]) * inv;
                const ushort4 st = {f2bf(o0), f2bf(o1), f2bf(o2), f2bf(o3)};
                *reinterpret_cast<ushort4*>(
                    &attn[(size_t)grow * 1024 + h * 64 + db * 16 + quad * 4]) = st;
                sum += (o0 + o1) + (o2 + o3);
                s2  += (o0 * o0 + o1 * o1) + (o2 * o2 + o3 * o3);
            }
            sum += __shfl_xor(sum, 16, 64); sum += __shfl_xor(sum, 32, 64);
            s2  += __shfl_xor(s2, 16, 64);  s2  += __shfl_xor(s2, 32, 64);
            if (quad == 0) part[(size_t)grow * 16 + h] = float2{sum, s2};
        }
    }
}

// ---------------- GEMM2: attn(bf16,raw) @ Wg^T, LN2 + rowstats fused.
// Tile 128(m) x 64(n) -> grid 512 = 2 blocks/CU.
__global__ __launch_bounds__(256) void gemm_proj(const unsigned short* __restrict__ A,
                                                 const unsigned short* __restrict__ Bt,
                                                 const float2* __restrict__ part,
                                                 const float* __restrict__ u,
                                                 const float* __restrict__ w0,
                                                 const float* __restrict__ bias,
                                                 float* __restrict__ out) {
    __shared__ unsigned short As[2 * 128 * 64];   // 32 KB
    __shared__ unsigned short Bs[2 * 64 * 64];    // 16 KB
    __shared__ float2 rstat_s[128];
    const int tid = threadIdx.x, lane = tid & 63, w = tid >> 6;
    const int quad = lane >> 4, l16 = lane & 15;
    const int ls = lane >> 3, sg = lane & 7;
    const int m0 = blockIdx.y * 128, n0 = blockIdx.x * 64;
    {   // rowstats for this block's 128 rows: 2 threads/row, 8 heads each
        const int rloc = tid >> 1, half = tid & 1;
        const float4* p4 = reinterpret_cast<const float4*>(part);
        float s = 0.f, s2 = 0.f;
#pragma unroll
        for (int j = 0; j < 4; j++) {
            const float4 p = p4[(size_t)(m0 + rloc) * 8 + half * 4 + j];
            s += p.x + p.z; s2 += p.y + p.w;
        }
        s  += __shfl_xor(s, 1, 64);
        s2 += __shfl_xor(s2, 1, 64);
        if (!half) {
            const float mu = s * (1.f / 1024.f);
            const float rstd = rsqrtf(s2 * (1.f / 1024.f) - mu * mu + 1e-5f);
            rstat_s[rloc] = float2{rstd, mu * rstd};
        }
    }   // ordered before use by the K-loop's first __syncthreads()

    float4v acc[2][4];
#pragma unroll
    for (int mi = 0; mi < 2; mi++)
#pragma unroll
        for (int ni = 0; ni < 4; ni++) acc[mi][ni] = float4v{0.f, 0.f, 0.f, 0.f};

    const int g = (sg ^ ls) * 8;
    // stage step 0
#pragma unroll
    for (int i = 0; i < 4; i++)
        gll16(&A[(size_t)(m0 + w * 32 + i * 8 + ls) * 1024 + g], &As[(w * 32 + i * 8) * 64]);
#pragma unroll
    for (int i = 0; i < 2; i++)
        gll16(&Bt[(size_t)(n0 + w * 16 + i * 8 + ls) * 1024 + g], &Bs[(w * 16 + i * 8) * 64]);

#pragma unroll 1
    for (int s = 0; s < 16; s++) {
        __syncthreads();
        if (s + 1 < 16) {
            const int k0 = (s + 1) << 6;
            unsigned short* Ad = As + (((s + 1) & 1) << 13);
            unsigned short* Bd = Bs + (((s + 1) & 1) << 12);
#pragma unroll
            for (int i = 0; i < 4; i++)
                gll16(&A[(size_t)(m0 + w * 32 + i * 8 + ls) * 1024 + k0 + g],
                      &Ad[(w * 32 + i * 8) * 64]);
#pragma unroll
            for (int i = 0; i < 2; i++)
                gll16(&Bt[(size_t)(n0 + w * 16 + i * 8 + ls) * 1024 + k0 + g],
                      &Bd[(w * 16 + i * 8) * 64]);
        }
        const unsigned short* Ac = As + ((s & 1) << 13);
        const unsigned short* Bc = Bs + ((s & 1) << 12);
#pragma unroll
        for (int ks = 0; ks < 2; ks++) {
            short8 af[2], bfr[4];
#pragma unroll
            for (int mi = 0; mi < 2; mi++) {
                const int r = w * 32 + mi * 16 + l16;
                af[mi] = *reinterpret_cast<const short8*>(
                    &Ac[r * 64 + ((ks * 4 + quad) ^ (r & 7)) * 8]);
            }
#pragma unroll
            for (int ni = 0; ni < 4; ni++) {
                const int r = ni * 16 + l16;
                bfr[ni] = *reinterpret_cast<const short8*>(
                    &Bc[r * 64 + ((ks * 4 + quad) ^ (r & 7)) * 8]);
            }
#pragma unroll
            for (int mi = 0; mi < 2; mi++)
#pragma unroll
                for (int ni = 0; ni < 4; ni++)
                    acc[mi][ni] = __builtin_amdgcn_mfma_f32_16x16x32_bf16(
                        af[mi], bfr[ni], acc[mi][ni], 0, 0, 0);
        }
    }

#pragma unroll
    for (int mi = 0; mi < 2; mi++) {
        const int rl0 = w * 32 + mi * 16 + quad * 4;
        float2 rs[4];
#pragma unroll
        for (int r = 0; r < 4; r++) rs[r] = rstat_s[rl0 + r];
#pragma unroll
        for (int ni = 0; ni < 4; ni++) {
            const int col = n0 + ni * 16 + l16;
            const float uu = u[col], ww = w0[col] + bias[col];
#pragma unroll
            for (int r = 0; r < 4; r++)
                out[(size_t)(m0 + rl0 + r) * 1024 + col] =
                    fmaf(rs[r].x, acc[mi][ni][r], ww - rs[r].y * uu);
        }
    }
}

extern "C" void kernel_launch(void* const* d_in, const int* in_sizes, int n_in,
                              void* d_out, int out_size, void* d_ws, size_t ws_size,
                              hipStream_t stream) {
    const float* x      = (const float*)d_in[0];
    const float* ln1_g  = (const float*)d_in[1];
    const float* ln1_b  = (const float*)d_in[2];
    const float* w_qk   = (const float*)d_in[3];
    const float* w_v    = (const float*)d_in[4];
    const float* ln2_g  = (const float*)d_in[5];
    const float* ln2_b  = (const float*)d_in[6];
    const float* w_proj = (const float*)d_in[7];
    const float* b_proj = (const float*)d_in[8];
    float* out = (float*)d_out;

    char* ws = (char*)d_ws;
    unsigned short* xn      = (unsigned short*)(ws + 0);         // 8MB  4096x1024 bf16
    unsigned short* wqkvT   = (unsigned short*)(ws + 8388608);   // 6MB  3072x1024 bf16
    unsigned short* wgT     = (unsigned short*)(ws + 14680064);  // 2MB  1024x1024 bf16 (g2-scaled w_proj^T)
    unsigned short* qbuf    = (unsigned short*)(ws + 16777216);  // 8MB  [32][2048][64]
    unsigned short* kbuf    = (unsigned short*)(ws + 25165824);  // 8MB  [32][2048][64]
    unsigned short* vTbuf   = (unsigned short*)(ws + 33554432);  // 8MB  [32][64][2048]
    unsigned short* attn    = (unsigned short*)(ws + 41943040);  // 8MB  4096x1024 bf16 (raw, pre-LN2)
    float2*         part    = (float2*)(ws + 50331648);          // 512KB [4096][16]
    float*          u       = (float*)(ws + 50888704);           // 4KB
    float*          w0      = (float*)(ws + 50892800);           // 4KB

    hipMemsetAsync(ws + 50888704, 0, 8192, stream);              // zero u + w0
    prep<<<5120, 256, 0, stream>>>(x, ln1_g, ln1_b, w_qk, w_v, w_proj, ln2_g, ln2_b,
                                   xn, wqkvT, wgT, u, w0);
    gemm_qkv<<<dim3(16, 32), 512, 0, stream>>>(xn, wqkvT, qbuf, kbuf, vTbuf);
    flash_attn<<<dim3(32, 16), 256, 0, stream>>>(qbuf, kbuf, vTbuf, attn, part);
    gemm_proj<<<dim3(16, 32), 256, 0, stream>>>(attn, wgT, part, u, w0, b_proj, out);
}

// Round 13
// 185.588 us; speedup vs baseline: 1.0420x; 1.0420x over previous
//
#include <hip/hip_runtime.h>
#include <hip/hip_bf16.h>

// B=2, N=2048, C=1024, H=16, hd=64, M=4096. bf16 MFMA path (threshold 2%).
// R13 build == R8's PASSED-AND-MEASURED source (186.8 us): prep v2 +
// gemm_qkv v4 + flash v11 + gemm_proj. Reverting to known-good after three
// consecutive infra failures on the (never-measured) R7-prep combo.

typedef __attribute__((ext_vector_type(8))) short short8;
typedef __attribute__((ext_vector_type(4))) short short4v;
typedef __attribute__((ext_vector_type(4))) float float4v;
typedef __attribute__((ext_vector_type(4))) unsigned uint4v;

__device__ __forceinline__ unsigned short f2bf(float f) {   // RTNE
    unsigned u = __builtin_bit_cast(unsigned, f);
    return (unsigned short)((u + 0x7FFFu + ((u >> 16) & 1u)) >> 16);
}
// hardware packed f32->bf16 (RTNE), lo in low half
__device__ __forceinline__ unsigned cvtpk(float lo, float hi) {
    unsigned r;
    asm("v_cvt_pk_bf16_f32 %0, %1, %2" : "=v"(r) : "v"(lo), "v"(hi));
    return r;
}
__device__ __forceinline__ void gll16(const unsigned short* g, unsigned short* l) {
    __builtin_amdgcn_global_load_lds(
        (const __attribute__((address_space(1))) unsigned int*)g,
        (__attribute__((address_space(3))) unsigned int*)l, 16, 0, 0);
}

// ---------------- prep v2: LN1 wave-per-row (blocks 0..1023, 4 rows/block —
// no __syncthreads, no LDS in the LN path) + weight transposes (1024..5119).
__global__ __launch_bounds__(256) void prep(
    const float* __restrict__ x, const float* __restrict__ g1, const float* __restrict__ b1,
    const float* __restrict__ w_qk, const float* __restrict__ w_v,
    const float* __restrict__ w_proj, const float* __restrict__ g2,
    const float* __restrict__ b2,
    unsigned short* __restrict__ xn, unsigned short* __restrict__ wqkvT,
    unsigned short* __restrict__ wgT, float* __restrict__ u, float* __restrict__ w0) {
    __shared__ float sh[32 * 33];
    const int bid = blockIdx.x, tid = threadIdx.x;
    if (bid < 1024) {                       // ---- LN1: one wave per row
        const int lane = tid & 63;
        const int row = bid * 4 + (tid >> 6);
        const float4* xr = reinterpret_cast<const float4*>(x + (size_t)row * 1024);
        const float4* G4 = reinterpret_cast<const float4*>(g1);
        const float4* B4 = reinterpret_cast<const float4*>(b1);
        float4 v[4];
        float s = 0.f, sq = 0.f;
#pragma unroll
        for (int i = 0; i < 4; i++) {
            v[i] = xr[i * 64 + lane];
            s  += (v[i].x + v[i].y) + (v[i].z + v[i].w);
            sq += (v[i].x * v[i].x + v[i].y * v[i].y) + (v[i].z * v[i].z + v[i].w * v[i].w);
        }
#pragma unroll
        for (int off = 32; off >= 1; off >>= 1) {
            s  += __shfl_xor(s, off, 64);
            sq += __shfl_xor(sq, off, 64);
        }
        const float mu = s * (1.f / 1024.f);
        const float rstd = rsqrtf(sq * (1.f / 1024.f) - mu * mu + 1e-5f);
#pragma unroll
        for (int i = 0; i < 4; i++) {
            const float4 gv = G4[i * 64 + lane], bv = B4[i * 64 + lane];
            ushort4 o;
            o.x = f2bf((v[i].x - mu) * rstd * gv.x + bv.x);
            o.y = f2bf((v[i].y - mu) * rstd * gv.y + bv.y);
            o.z = f2bf((v[i].z - mu) * rstd * gv.z + bv.z);
            o.w = f2bf((v[i].w - mu) * rstd * gv.w + bv.w);
            *reinterpret_cast<ushort4*>(&xn[(size_t)row * 1024 + i * 256 + lane * 4]) = o;
        }
    } else {                                // ---- transpose f32[1024][Cc] -> bf16[Cc][1024]
        const float* in; unsigned short* out; int Cc, bx, by; bool doU = false;
        if (bid < 3072)      { int t = bid - 1024; in = w_qk;   out = wqkvT;               Cc = 2048; bx = t & 63; by = t >> 6; }
        else if (bid < 4096) { int t = bid - 3072; in = w_v;    out = wqkvT + 2048 * 1024; Cc = 1024; bx = t & 31; by = t >> 5; }
        else                 { int t = bid - 4096; in = w_proj; out = wgT; doU = true;     Cc = 1024; bx = t & 31; by = t >> 5; }
        const int c0 = bx * 32, r0 = by * 32;
        const int tx = tid & 31, ty = tid >> 5;
#pragma unroll
        for (int i = 0; i < 32; i += 8)
            sh[(ty + i) * 33 + tx] = in[(size_t)(r0 + ty + i) * Cc + c0 + tx];
        __syncthreads();
        // out col = original row index c = r0+tx
        const float scale = doU ? g2[r0 + tx] : 1.f;
        const float b2v   = doU ? b2[r0 + tx] : 0.f;
#pragma unroll
        for (int i = 0; i < 32; i += 8) {
            const float raw = sh[tx * 33 + ty + i];
            const float sc  = raw * scale;
            out[(size_t)(c0 + ty + i) * 1024 + r0 + tx] = f2bf(sc);
            if (doU) {
                float pu = sc, pw = raw * b2v;    // per-c contributions for j=c0+ty+i
#pragma unroll
                for (int off = 1; off <= 16; off <<= 1) {   // reduce over tx (32 lanes)
                    pu += __shfl_xor(pu, off, 64);
                    pw += __shfl_xor(pw, off, 64);
                }
                if (tx == 0) {
                    atomicAdd(&u[c0 + ty + i], pu);
                    atomicAdd(&w0[c0 + ty + i], pw);
                }
            }
        }
    }
}

// ---------------- GEMM1 v4 (R7/R8-verified, sub-47): 128(m) x 192(n) tile,
// 512 thr / 8 waves (2m x 4n, acc 4x3), BK=64, 2-dbuf. LDS 80 KB ->
// 2 blocks/CU; grid 16x32 = 512 = exactly 2/CU, uniform. Unchanged.
__global__ __launch_bounds__(512, 2) void gemm_qkv(const unsigned short* __restrict__ A,
                                                   const unsigned short* __restrict__ Bt,
                                                   unsigned short* __restrict__ qb,
                                                   unsigned short* __restrict__ kb,
                                                   unsigned short* __restrict__ vT) {
    __shared__ unsigned short As[2 * 128 * 64];   // 32 KB
    __shared__ unsigned short Bs[2 * 192 * 64];   // 48 KB
    const int tid = threadIdx.x, lane = tid & 63, w = tid >> 6;     // w 0..7
    const int wm = (w >> 2) * 64, wn = (w & 3) * 48;
    const int quad = lane >> 4, l16 = lane & 15;
    const int ls = lane >> 3, sg = lane & 7;
    const int m0 = blockIdx.y * 128, n0 = blockIdx.x * 192;

    float4v acc[4][3];
#pragma unroll
    for (int mi = 0; mi < 4; mi++)
#pragma unroll
        for (int ni = 0; ni < 3; ni++) acc[mi][ni] = float4v{0.f, 0.f, 0.f, 0.f};

    const int g = (sg ^ ls) * 8;
    // stage step 0: per wave 16 A-rows (2 gll16) + 24 B-rows (3 gll16)
#pragma unroll
    for (int i = 0; i < 2; i++)
        gll16(&A[(size_t)(m0 + w * 16 + i * 8 + ls) * 1024 + g], &As[(w * 16 + i * 8) * 64]);
#pragma unroll
    for (int i = 0; i < 3; i++)
        gll16(&Bt[(size_t)(n0 + w * 24 + i * 8 + ls) * 1024 + g], &Bs[(w * 24 + i * 8) * 64]);

#pragma unroll 1
    for (int s = 0; s < 16; s++) {
        __syncthreads();
        if (s + 1 < 16) {                   // stage step s+1 (overlaps compute(s))
            const int k0 = (s + 1) << 6;
            unsigned short* Ad = As + (((s + 1) & 1) << 13);
            unsigned short* Bd = Bs + (((s + 1) & 1) * 12288);
#pragma unroll
            for (int i = 0; i < 2; i++)
                gll16(&A[(size_t)(m0 + w * 16 + i * 8 + ls) * 1024 + k0 + g],
                      &Ad[(w * 16 + i * 8) * 64]);
#pragma unroll
            for (int i = 0; i < 3; i++)
                gll16(&Bt[(size_t)(n0 + w * 24 + i * 8 + ls) * 1024 + k0 + g],
                      &Bd[(w * 24 + i * 8) * 64]);
        }
        const unsigned short* Ac = As + ((s & 1) << 13);
        const unsigned short* Bc = Bs + ((s & 1) * 12288);
#pragma unroll
        for (int ks = 0; ks < 2; ks++) {
            short8 af[4], bfr[3];
#pragma unroll
            for (int mi = 0; mi < 4; mi++) {
                const int r = wm + mi * 16 + l16;
                af[mi] = *reinterpret_cast<const short8*>(
                    &Ac[r * 64 + ((ks * 4 + quad) ^ (r & 7)) * 8]);
            }
#pragma unroll
            for (int ni = 0; ni < 3; ni++) {
                const int r = wn + ni * 16 + l16;
                bfr[ni] = *reinterpret_cast<const short8*>(
                    &Bc[r * 64 + ((ks * 4 + quad) ^ (r & 7)) * 8]);
            }
#pragma unroll
            for (int mi = 0; mi < 4; mi++)
#pragma unroll
                for (int ni = 0; ni < 3; ni++)
                    acc[mi][ni] = __builtin_amdgcn_mfma_f32_16x16x32_bf16(
                        af[mi], bfr[ni], acc[mi][ni], 0, 0, 0);
        }
    }

    const float QSCALE = 0.125f * 1.4426950408889634f;  // hd^-0.5 * log2(e)
#pragma unroll
    for (int mi = 0; mi < 4; mi++) {
        const int row0 = m0 + wm + mi * 16 + quad * 4;
        const int b = row0 >> 11, nq = row0 & 2047;
#pragma unroll
        for (int ni = 0; ni < 3; ni++) {
            const int col = n0 + wn + ni * 16 + l16;
            if (col < 1024) {             // q: [bh][n][d]
                const int h = col >> 6, d = col & 63;
#pragma unroll
                for (int r = 0; r < 4; r++)
                    qb[(((size_t)b * 16 + h) * 2048 + nq + r) * 64 + d] =
                        f2bf(acc[mi][ni][r] * QSCALE);
            } else if (col < 2048) {      // k: [bh][n][d]
                const int c = col - 1024, h = c >> 6, d = c & 63;
#pragma unroll
                for (int r = 0; r < 4; r++)
                    kb[(((size_t)b * 16 + h) * 2048 + nq + r) * 64 + d] = f2bf(acc[mi][ni][r]);
            } else {                      // v^T: [bh][d][n], 4 consecutive keys -> 8B store
                const int c = col - 2048, h = c >> 6, d = c & 63;
                const short4v sv = {(short)f2bf(acc[mi][ni][0]), (short)f2bf(acc[mi][ni][1]),
                                    (short)f2bf(acc[mi][ni][2]), (short)f2bf(acc[mi][ni][3])};
                *reinterpret_cast<short4v*>(
                    &vT[(((size_t)b * 16 + h) * 64 + d) * 2048 + nq]) = sv;
            }
        }
    }
}

// ---------------- flash attention v11 (R8-measured floor: 46.8 us).
// 512 thr / 8 waves, key-split wave pairs, 128-KEY stages (16 barriers),
// 66 KB LDS, bh-fastest grid (FETCH 12.3 MB). Unchanged from R8.
__global__ __launch_bounds__(512, 4) void flash_attn(const unsigned short* __restrict__ qbuf,
                                                     const unsigned short* __restrict__ kb,
                                                     const unsigned short* __restrict__ vT,
                                                     unsigned short* __restrict__ attn,
                                                     float2* __restrict__ part) {
    __shared__ __align__(16) unsigned short KB[2][2][64 * 64];  // K dbuf x 2 sub-tiles, 32 KB
    __shared__ __align__(16) unsigned short VB[2][2][64 * 64];  // V dbuf x 2 sub-tiles, 32 KB
    __shared__ float lsh[4][2][64];                             // l partials kh=1 -> kh=0, 2 KB
    const int tid = threadIdx.x, lane = tid & 63, w = tid >> 6;   // w 0..7
    const int wq = w & 3, kh = w >> 2;
    const int quad = lane >> 4, l16 = lane & 15;
    const int ls = lane >> 3, sg = lane & 7;
    const int bh = blockIdx.x, q0 = blockIdx.y * 128;
    const size_t nbase = (size_t)bh * 2048;

    // K staging: phys row pr holds actual key ka = [bit5][quad(2b)][cb&1][reg]
    const int pr = w * 8 + ls;
    const int srow = (pr & 32) | ((pr & 12) << 1) | ((pr & 16) >> 2) | (pr & 3);
    const int sgran = (sg ^ ls) << 3;

    short8 bq[2][2];   // Q as B-operand, q = q0 + wq*32 + q2*16 + l16
#pragma unroll
    for (int q2 = 0; q2 < 2; q2++)
#pragma unroll
        for (int ks = 0; ks < 2; ks++)
            bq[q2][ks] = *reinterpret_cast<const short8*>(
                &qbuf[(nbase + q0 + wq * 32 + q2 * 16 + l16) * 64 + ks * 32 + quad * 8]);

    float l_part[2] = {0.f, 0.f};
    float4v o_acc[2][4];   // o_acc[q2][db]: d = db*16+quad*4+reg, q = l16 (partial: kh half)
#pragma unroll
    for (int q2 = 0; q2 < 2; q2++)
#pragma unroll
        for (int db = 0; db < 4; db++) o_acc[q2][db] = float4v{0.f, 0.f, 0.f, 0.f};

    // stage(t, buf): 128 keys = two 64-key sub-tiles; 4 gll16/wave
#define FSTAGE(t, buf)                                                                  \
    _Pragma("unroll")                                                                   \
    for (int t2 = 0; t2 < 2; t2++) {                                                    \
        gll16(&kb[(nbase + (t) * 128 + t2 * 64 + srow) * 64 + sgran],                   \
              &KB[buf][t2][w * 8 * 64]);                                                \
        gll16(&vT[((size_t)bh * 64 + w * 8 + ls) * 2048 + (t) * 128 + t2 * 64 + sgran], \
              &VB[buf][t2][w * 8 * 64]);                                                \
    }

    FSTAGE(0, 0);

#pragma unroll 1
    for (int s = 0; s < 16; s++) {
        __syncthreads();                    // drains stage-s DMA
        if (s + 1 < 16) FSTAGE(s + 1, (s + 1) & 1);   // drained at next barrier

#pragma unroll
        for (int t2 = 0; t2 < 2; t2++) {
            const unsigned short* Kc = KB[s & 1][t2];
            const unsigned short* Vc = VB[s & 1][t2];

            // this wave's 32-key half: phys rows kh*32 + cc*16 + l16
            short8 kf[2][2];
#pragma unroll
            for (int ks = 0; ks < 2; ks++)
#pragma unroll
                for (int cc = 0; cc < 2; cc++) {
                    const int r = kh * 32 + cc * 16 + l16;
                    kf[ks][cc] = *reinterpret_cast<const short8*>(
                        &Kc[r * 64 + ((ks * 4 + quad) ^ (r & 7)) * 8]);
                }
            // V^T A-fragments for this key half: A[d=db*16+l16][k = kh*32 + quad*8 + j]
            short8 va[4];
#pragma unroll
            for (int db = 0; db < 4; db++) {
                const int r = db * 16 + l16;
                va[db] = *reinterpret_cast<const short8*>(
                    &Vc[r * 64 + ((kh * 4 + quad) ^ (r & 7)) * 8]);
            }

#pragma unroll
            for (int q2 = 0; q2 < 2; q2++) {
                float4v s_acc[2];
#pragma unroll
                for (int cc = 0; cc < 2; cc++) s_acc[cc] = float4v{0.f, 0.f, 0.f, 0.f};
                __builtin_amdgcn_s_setprio(1);
#pragma unroll
                for (int ks = 0; ks < 2; ks++)
#pragma unroll
                    for (int cc = 0; cc < 2; cc++)
                        s_acc[cc] = __builtin_amdgcn_mfma_f32_16x16x32_bf16(
                            kf[ks][cc], bq[q2][ks], s_acc[cc], 0, 0, 0);
                __builtin_amdgcn_s_setprio(0);

                // fixed-max softmax: p = 2^s. Permuted K rows make the pack
                // register-local: actual key = kh*32 + quad*8 + cc*4 + reg.
                float ls2 = 0.f;
                float p[8];
#pragma unroll
                for (int cc = 0; cc < 2; cc++)
#pragma unroll
                    for (int r = 0; r < 4; r++) {
                        const float pv = __builtin_amdgcn_exp2f(s_acc[cc][r]);
                        p[cc * 4 + r] = pv;
                        ls2 += pv;
                    }
                uint4v pd;
                pd.x = cvtpk(p[0], p[1]); pd.y = cvtpk(p[2], p[3]);
                pd.z = cvtpk(p[4], p[5]); pd.w = cvtpk(p[6], p[7]);
                const short8 pb = __builtin_bit_cast(short8, pd);
                l_part[q2] += ls2;
                __builtin_amdgcn_s_setprio(1);
#pragma unroll
                for (int db = 0; db < 4; db++)
                    o_acc[q2][db] = __builtin_amdgcn_mfma_f32_16x16x32_bf16(
                        va[db], pb, o_acc[q2][db], 0, 0, 0);
                __builtin_amdgcn_s_setprio(0);
            }
        }
    }
#undef FSTAGE

    // ---- combine key halves through LDS (K buffers are dead now).
    __syncthreads();                        // all waves done reading K/V
    float* osh = reinterpret_cast<float*>(KB);   // 8192 floats = 32 KB exactly
    const int swz = (l16 & 7) << 2;              // 16B-granule XOR to spread banks
    if (kh == 1) {
#pragma unroll
        for (int q2 = 0; q2 < 2; q2++) {
#pragma unroll
            for (int db = 0; db < 4; db++) {
                const int base = (wq * 32 + q2 * 16 + l16) * 64 + db * 16 + quad * 4;
                *reinterpret_cast<float4v*>(&osh[base ^ swz]) = o_acc[q2][db];
            }
            lsh[wq][q2][lane] = l_part[q2];
        }
    }
    __syncthreads();
    if (kh == 0) {
        const int b = bh >> 4, h = bh & 15;
#pragma unroll
        for (int q2 = 0; q2 < 2; q2++) {
            float lr = l_part[q2] + lsh[wq][q2][lane];
            lr += __shfl_xor(lr, 16, 64);
            lr += __shfl_xor(lr, 32, 64);
            const float inv = 1.f / lr;
            const int grow = b * 2048 + q0 + wq * 32 + q2 * 16 + l16;
            float sum = 0.f, s2 = 0.f;
#pragma unroll
            for (int db = 0; db < 4; db++) {
                const int base = (wq * 32 + q2 * 16 + l16) * 64 + db * 16 + quad * 4;
                const float4v oh = *reinterpret_cast<const float4v*>(&osh[base ^ swz]);
                const float o0 = (o_acc[q2][db][0] + oh[0]) * inv;
                const float o1 = (o_acc[q2][db][1] + oh[1]) * inv;
                const float o2 = (o_acc[q2][db][2] + oh[2]) * inv;
                const float o3 = (o_acc[q2][db][3] + oh[3]) * inv;
                const ushort4 st = {f2bf(o0), f2bf(o1), f2bf(o2), f2bf(o3)};
                *reinterpret_cast<ushort4*>(
                    &attn[(size_t)grow * 1024 + h * 64 + db * 16 + quad * 4]) = st;
                sum += (o0 + o1) + (o2 + o3);
                s2  += (o0 * o0 + o1 * o1) + (o2 * o2 + o3 * o3);
            }
            sum += __shfl_xor(sum, 16, 64); sum += __shfl_xor(sum, 32, 64);
            s2  += __shfl_xor(s2, 16, 64);  s2  += __shfl_xor(s2, 32, 64);
            if (quad == 0) part[(size_t)grow * 16 + h] = float2{sum, s2};
        }
    }
}

// ---------------- GEMM2: attn(bf16,raw) @ Wg^T, LN2 + rowstats fused.
// Tile 128(m) x 64(n) -> grid 512 = 2 blocks/CU.
__global__ __launch_bounds__(256) void gemm_proj(const unsigned short* __restrict__ A,
                                                 const unsigned short* __restrict__ Bt,
                                                 const float2* __restrict__ part,
                                                 const float* __restrict__ u,
                                                 const float* __restrict__ w0,
                                                 const float* __restrict__ bias,
                                                 float* __restrict__ out) {
    __shared__ unsigned short As[2 * 128 * 64];   // 32 KB
    __shared__ unsigned short Bs[2 * 64 * 64];    // 16 KB
    __shared__ float2 rstat_s[128];
    const int tid = threadIdx.x, lane = tid & 63, w = tid >> 6;
    const int quad = lane >> 4, l16 = lane & 15;
    const int ls = lane >> 3, sg = lane & 7;
    const int m0 = blockIdx.y * 128, n0 = blockIdx.x * 64;
    {   // rowstats for this block's 128 rows: 2 threads/row, 8 heads each
        const int rloc = tid >> 1, half = tid & 1;
        const float4* p4 = reinterpret_cast<const float4*>(part);
        float s = 0.f, s2 = 0.f;
#pragma unroll
        for (int j = 0; j < 4; j++) {
            const float4 p = p4[(size_t)(m0 + rloc) * 8 + half * 4 + j];
            s += p.x + p.z; s2 += p.y + p.w;
        }
        s  += __shfl_xor(s, 1, 64);
        s2 += __shfl_xor(s2, 1, 64);
        if (!half) {
            const float mu = s * (1.f / 1024.f);
            const float rstd = rsqrtf(s2 * (1.f / 1024.f) - mu * mu + 1e-5f);
            rstat_s[rloc] = float2{rstd, mu * rstd};
        }
    }   // ordered before use by the K-loop's first __syncthreads()

    float4v acc[2][4];
#pragma unroll
    for (int mi = 0; mi < 2; mi++)
#pragma unroll
        for (int ni = 0; ni < 4; ni++) acc[mi][ni] = float4v{0.f, 0.f, 0.f, 0.f};

    const int g = (sg ^ ls) * 8;
    // stage step 0
#pragma unroll
    for (int i = 0; i < 4; i++)
        gll16(&A[(size_t)(m0 + w * 32 + i * 8 + ls) * 1024 + g], &As[(w * 32 + i * 8) * 64]);
#pragma unroll
    for (int i = 0; i < 2; i++)
        gll16(&Bt[(size_t)(n0 + w * 16 + i * 8 + ls) * 1024 + g], &Bs[(w * 16 + i * 8) * 64]);

#pragma unroll 1
    for (int s = 0; s < 16; s++) {
        __syncthreads();
        if (s + 1 < 16) {
            const int k0 = (s + 1) << 6;
            unsigned short* Ad = As + (((s + 1) & 1) << 13);
            unsigned short* Bd = Bs + (((s + 1) & 1) << 12);
#pragma unroll
            for (int i = 0; i < 4; i++)
                gll16(&A[(size_t)(m0 + w * 32 + i * 8 + ls) * 1024 + k0 + g],
                      &Ad[(w * 32 + i * 8) * 64]);
#pragma unroll
            for (int i = 0; i < 2; i++)
                gll16(&Bt[(size_t)(n0 + w * 16 + i * 8 + ls) * 1024 + k0 + g],
                      &Bd[(w * 16 + i * 8) * 64]);
        }
        const unsigned short* Ac = As + ((s & 1) << 13);
        const unsigned short* Bc = Bs + ((s & 1) << 12);
#pragma unroll
        for (int ks = 0; ks < 2; ks++) {
            short8 af[2], bfr[4];
#pragma unroll
            for (int mi = 0; mi < 2; mi++) {
                const int r = w * 32 + mi * 16 + l16;
                af[mi] = *reinterpret_cast<const short8*>(
                    &Ac[r * 64 + ((ks * 4 + quad) ^ (r & 7)) * 8]);
            }
#pragma unroll
            for (int ni = 0; ni < 4; ni++) {
                const int r = ni * 16 + l16;
                bfr[ni] = *reinterpret_cast<const short8*>(
                    &Bc[r * 64 + ((ks * 4 + quad) ^ (r & 7)) * 8]);
            }
#pragma unroll
            for (int mi = 0; mi < 2; mi++)
#pragma unroll
                for (int ni = 0; ni < 4; ni++)
                    acc[mi][ni] = __builtin_amdgcn_mfma_f32_16x16x32_bf16(
                        af[mi], bfr[ni], acc[mi][ni], 0, 0, 0);
        }
    }

#pragma unroll
    for (int mi = 0; mi < 2; mi++) {
        const int rl0 = w * 32 + mi * 16 + quad * 4;
        float2 rs[4];
#pragma unroll
        for (int r = 0; r < 4; r++) rs[r] = rstat_s[rl0 + r];
#pragma unroll
        for (int ni = 0; ni < 4; ni++) {
            const int col = n0 + ni * 16 + l16;
            const float uu = u[col], ww = w0[col] + bias[col];
#pragma unroll
            for (int r = 0; r < 4; r++)
                out[(size_t)(m0 + rl0 + r) * 1024 + col] =
                    fmaf(rs[r].x, acc[mi][ni][r], ww - rs[r].y * uu);
        }
    }
}

extern "C" void kernel_launch(void* const* d_in, const int* in_sizes, int n_in,
                              void* d_out, int out_size, void* d_ws, size_t ws_size,
                              hipStream_t stream) {
    const float* x      = (const float*)d_in[0];
    const float* ln1_g  = (const float*)d_in[1];
    const float* ln1_b  = (const float*)d_in[2];
    const float* w_qk   = (const float*)d_in[3];
    const float* w_v    = (const float*)d_in[4];
    const float* ln2_g  = (const float*)d_in[5];
    const float* ln2_b  = (const float*)d_in[6];
    const float* w_proj = (const float*)d_in[7];
    const float* b_proj = (const float*)d_in[8];
    float* out = (float*)d_out;

    char* ws = (char*)d_ws;
    unsigned short* xn      = (unsigned short*)(ws + 0);         // 8MB  4096x1024 bf16
    unsigned short* wqkvT   = (unsigned short*)(ws + 8388608);   // 6MB  3072x1024 bf16
    unsigned short* wgT     = (unsigned short*)(ws + 14680064);  // 2MB  1024x1024 bf16 (g2-scaled w_proj^T)
    unsigned short* qbuf    = (unsigned short*)(ws + 16777216);  // 8MB  [32][2048][64]
    unsigned short* kbuf    = (unsigned short*)(ws + 25165824);  // 8MB  [32][2048][64]
    unsigned short* vTbuf   = (unsigned short*)(ws + 33554432);  // 8MB  [32][64][2048]
    unsigned short* attn    = (unsigned short*)(ws + 41943040);  // 8MB  4096x1024 bf16 (raw, pre-LN2)
    float2*         part    = (float2*)(ws + 50331648);          // 512KB [4096][16]
    float*          u       = (float*)(ws + 50888704);           // 4KB
    float*          w0      = (float*)(ws + 50892800);           // 4KB

    hipMemsetAsync(ws + 50888704, 0, 8192, stream);              // zero u + w0
    prep<<<5120, 256, 0, stream>>>(x, ln1_g, ln1_b, w_qk, w_v, w_proj, ln2_g, ln2_b,
                                   xn, wqkvT, wgT, u, w0);
    gemm_qkv<<<dim3(16, 32), 512, 0, stream>>>(xn, wqkvT, qbuf, kbuf, vTbuf);
    flash_attn<<<dim3(32, 16), 512, 0, stream>>>(qbuf, kbuf, vTbuf, attn, part);
    gemm_proj<<<dim3(16, 32), 256, 0, stream>>>(attn, wgT, part, u, w0, b_proj, out);
}